// Round 8
// baseline (17678.401 us; speedup 1.0000x reference)
//
#include <hip/hip_runtime.h>
#include <hip/hip_fp16.h>

#define BSZ   64
#define ILEN  1024
#define TLEN  1024
#define TTOT  2048
#define IDIM  128
#define HDIM  256
#define GDIM  1024   // 4*HDIM
#define NCLS  128
#define NGRP  4      // batch groups of 16
#define NMEM  4      // member blocks per group (64 units each)
#define BPG   16     // batches per group

typedef unsigned int u32;
typedef _Float16 f16x8 __attribute__((ext_vector_type(8)));
typedef float f32x4 __attribute__((ext_vector_type(4)));
typedef _Float16 h2_t __attribute__((ext_vector_type(2)));

union U4H8 { uint4 u; f16x8 h; };

__device__ __forceinline__ float fdot2(u32 a, u32 b, float acc) {
#if __has_builtin(__builtin_amdgcn_fdot2)
    union { u32 u; h2_t h; } ua, ub;
    ua.u = a; ub.u = b;
    return __builtin_amdgcn_fdot2(ua.h, ub.h, acc, false);
#else
    union { u32 u; __half2 h; } ua, ub;
    ua.u = a; ub.u = b;
    return acc + __low2float(ua.h) * __low2float(ub.h)
               + __high2float(ua.h) * __high2float(ub.h);
#endif
}

__device__ __forceinline__ u32 packf2(float x, float y) {
    __half2 h = __floats2half2_rn(x, y);
    union { __half2 h; u32 u; } c; c.h = h;
    return c.u;
}

__device__ __forceinline__ float sigm(float x) { return 1.f / (1.f + __expf(-x)); }
__device__ __forceinline__ float tanh_fast(float x) { return 1.f - 2.f / (__expf(2.f * x) + 1.f); }

// ---------------------------------------------------------------------------
// Pack weights into MFMA A-fragment order (f16). (Layouts verified by R6/R7
// passing absmax.)
//  Apack  (w_hh): chunk ci = ug*32 + g*8 + kt, lane l, j holds
//       w_hh[g*256 + ug*16 + (l&15)][kt*32 + (l>>4)*8 + j]
//  Aipack (w_ih): chunk ci = ug*16 + g*4 + kt4, same row, K = kt4*32+(l>>4)*8+j
//  Wcq    (clf):  [k4][n] uint4 layout for clf_kernel
// ---------------------------------------------------------------------------
__global__ void pack_kernel(const float* __restrict__ w_ih,
                            const float* __restrict__ w_hh,
                            const float* __restrict__ clf_w,
                            uint4* __restrict__ Apack,
                            uint4* __restrict__ Aipack,
                            uint4* __restrict__ Wcq)
{
    int i = blockIdx.x * blockDim.x + threadIdx.x;
    if (i < 32768) {                       // Apack: 512 chunks x 64 lanes
        int ci = i >> 6, l = i & 63;
        int ug = ci >> 5, g = (ci >> 3) & 3, kt = ci & 7;
        int R  = g * HDIM + ug * 16 + (l & 15);
        int K0 = kt * 32 + (l >> 4) * 8;
        const float* src = w_hh + (size_t)R * HDIM + K0;
        uint4 v;
        v.x = packf2(src[0], src[1]); v.y = packf2(src[2], src[3]);
        v.z = packf2(src[4], src[5]); v.w = packf2(src[6], src[7]);
        Apack[i] = v;
    } else if (i < 49152) {                // Aipack: 256 chunks x 64 lanes
        int r = i - 32768;
        int ci = r >> 6, l = r & 63;
        int ug = ci >> 4, g = (ci >> 2) & 3, kt4 = ci & 3;
        int R  = g * HDIM + ug * 16 + (l & 15);
        int K0 = kt4 * 32 + (l >> 4) * 8;
        const float* src = w_ih + (size_t)R * IDIM + K0;
        uint4 v;
        v.x = packf2(src[0], src[1]); v.y = packf2(src[2], src[3]);
        v.z = packf2(src[4], src[5]); v.w = packf2(src[6], src[7]);
        Aipack[r] = v;
    } else if (i < 53248) {                // Wcq (clf)
        int r = i - 49152;
        int n = r & (NCLS - 1);
        int k4 = r >> 7;
        const float* src = clf_w + (size_t)n * HDIM + k4 * 8;
        uint4 v;
        v.x = packf2(src[0], src[1]); v.y = packf2(src[2], src[3]);
        v.z = packf2(src[4], src[5]); v.w = packf2(src[6], src[7]);
        Wcq[r] = v;
    }
}

// ---------------------------------------------------------------------------
// Zero h-exchange buffers and flags every launch (ws poisoned 0xAA once;
// timing replays don't re-poison; flags must start at 0, h at exact 0).
// ---------------------------------------------------------------------------
__global__ void init_kernel(u32* __restrict__ hbuf, u32* __restrict__ flags)
{
    int i = blockIdx.x * blockDim.x + threadIdx.x;
    if (i < NGRP * 2 * BPG * 128) hbuf[i] = 0u;
    if (i < NGRP * 16) flags[i] = 0u;
}

// ---------------------------------------------------------------------------
// MFMA recurrent kernel, dual-group multiplexed, barrier-free inner loop.
// 8 blocks = 4 members x 2 group-pairs. Block (member, q) serves groups
// gA=2q, gB=2q+1 (16 batches each); wave w owns units [w*16,w*16+16) x all
// 4 gates => epilogue fully in-register, NO __syncthreads in the t-loop.
// Sync: per-wave flag slot (release store after vmcnt-drained publishes);
// readers acquire-poll (L1 invalidate) then plain dwordx4 h loads.
// ---------------------------------------------------------------------------
__global__ __launch_bounds__(256, 1) void lstm_rec(
    const float* __restrict__ inp,
    const float* __restrict__ bias_g,
    const uint4* __restrict__ Apack,
    const uint4* __restrict__ Aipack,
    __half* __restrict__ Hs,
    u32* __restrict__ hbuf,     // [NGRP][2][BPG][128] u32 (f16 pairs [b][u/2])
    u32* __restrict__ flags)    // [NGRP][16] (slot = member*4 + wave)
{
    __shared__ alignas(16) uint4 whA[128 * 64];   // 128 KB, member's w_hh

    const int blk    = blockIdx.x;     // 0..7
    const int member = blk & 3;
    const int q      = blk >> 2;       // pair 0..1
    const int gA     = q * 2 + 0;
    const int gB     = q * 2 + 1;
    const int tid = threadIdx.x;
    const int w   = tid >> 6;          // wave: units [w*16, w*16+16), all gates
    const int l   = tid & 63;
    const int lq  = l >> 4;            // k-quarter
    const int lm  = l & 15;            // A-row / B-col (batch within group)

    // stage member's w_hh A-fragments (identity copy: LDS chunk == Apack chunk)
    {
        const uint4* src = Apack + (size_t)member * 8192;
        #pragma unroll
        for (int s = 0; s < 32; ++s) whA[s * 256 + tid] = src[s * 256 + tid];
    }
    __syncthreads();   // the only block barrier

    f32x4 biasv[4];
    #pragma unroll
    for (int g = 0; g < 4; ++g) {
        const float* bp = bias_g + g * HDIM + member * 64 + w * 16 + lq * 4;
        biasv[g] = (f32x4){bp[0], bp[1], bp[2], bp[3]};
    }

    float cA[4] = {0.f, 0.f, 0.f, 0.f};
    float cB[4] = {0.f, 0.f, 0.f, 0.f};

    const uint4* hb4 = (const uint4*)hbuf;
    u32* flA = flags + gA * 16;
    u32* flB = flags + gB * 16;
    const int fidx = l & 15;
    const int fA = gA * 16 + member * 4 + w;
    const int fB = gB * 16 + member * 4 + w;

    for (int t = 0; t < TTOT; ++t) {
        const int par  = t & 1;
        const int par2 = (t + 1) & 1;

        // ---- x loads + f16 pack (flag-independent; fills poll wait)
        uint4 bxA[4], bxB[4];
        if (t < ILEN) {
            const float* xA = inp + ((size_t)(gA * 16 + lm) * ILEN + t) * IDIM + lq * 8;
            const float* xB = inp + ((size_t)(gB * 16 + lm) * ILEN + t) * IDIM + lq * 8;
            #pragma unroll
            for (int k4 = 0; k4 < 4; ++k4) {
                float4 a0 = *(const float4*)(xA + k4 * 32);
                float4 a1 = *(const float4*)(xA + k4 * 32 + 4);
                bxA[k4].x = packf2(a0.x, a0.y); bxA[k4].y = packf2(a0.z, a0.w);
                bxA[k4].z = packf2(a1.x, a1.y); bxA[k4].w = packf2(a1.z, a1.w);
                float4 b0 = *(const float4*)(xB + k4 * 32);
                float4 b1 = *(const float4*)(xB + k4 * 32 + 4);
                bxB[k4].x = packf2(b0.x, b0.y); bxB[k4].y = packf2(b0.z, b0.w);
                bxB[k4].z = packf2(b1.x, b1.y); bxB[k4].w = packf2(b1.z, b1.w);
            }
        }

        // ---- acquire-poll both groups (acquire load = L1 inv on success path)
        if (t > 0) {
            while (true) {
                u32 v = __hip_atomic_load(flA + fidx, __ATOMIC_ACQUIRE, __HIP_MEMORY_SCOPE_AGENT);
                if (__all(v >= (u32)t)) break;
                __builtin_amdgcn_s_sleep(1);
            }
            while (true) {
                u32 v = __hip_atomic_load(flB + fidx, __ATOMIC_ACQUIRE, __HIP_MEMORY_SCOPE_AGENT);
                if (__all(v >= (u32)t)) break;
                __builtin_amdgcn_s_sleep(1);
            }
        }

        // ---- h B-fragments: plain dwordx4 loads, pipelined
        uint4 hA[8], hB[8];
        {
            const uint4* pA = hb4 + ((size_t)(gA * 2 + par) * BPG + lm) * 32 + lq;
            const uint4* pB = hb4 + ((size_t)(gB * 2 + par) * BPG + lm) * 32 + lq;
            #pragma unroll
            for (int kt = 0; kt < 8; ++kt) { hA[kt] = pA[kt * 4]; hB[kt] = pB[kt * 4]; }
        }

        // ---- MFMAs, A-operand shared between the two groups
        f32x4 accA[4], accB[4];
        #pragma unroll
        for (int g = 0; g < 4; ++g) { accA[g] = biasv[g]; accB[g] = biasv[g]; }
        if (t < ILEN) {
            #pragma unroll
            for (int k4 = 0; k4 < 4; ++k4) {
                U4H8 bA, bB; bA.u = bxA[k4]; bB.u = bxB[k4];
                #pragma unroll
                for (int g = 0; g < 4; ++g) {
                    U4H8 a; a.u = Aipack[((size_t)(member * 4 + w) * 16 + g * 4 + k4) * 64 + l];
                    accA[g] = __builtin_amdgcn_mfma_f32_16x16x32_f16(a.h, bA.h, accA[g], 0, 0, 0);
                    accB[g] = __builtin_amdgcn_mfma_f32_16x16x32_f16(a.h, bB.h, accB[g], 0, 0, 0);
                }
            }
        }
        #pragma unroll
        for (int kt = 0; kt < 8; ++kt) {
            U4H8 bA, bB; bA.u = hA[kt]; bB.u = hB[kt];
            #pragma unroll
            for (int g = 0; g < 4; ++g) {
                U4H8 a; a.u = whA[((w * 4 + g) * 8 + kt) * 64 + l];
                accA[g] = __builtin_amdgcn_mfma_f32_16x16x32_f16(a.h, bA.h, accA[g], 0, 0, 0);
                accB[g] = __builtin_amdgcn_mfma_f32_16x16x32_f16(a.h, bB.h, accB[g], 0, 0, 0);
            }
        }

        // ---- in-register epilogue + publish (unit = w*16+lq*4+r, batch = lm)
        {
            float hv[4];
            #pragma unroll
            for (int r = 0; r < 4; ++r) {
                float ig = sigm(accA[0][r]);
                float fg = sigm(accA[1][r]);
                float gg = tanh_fast(accA[2][r]);
                float og = sigm(accA[3][r]);
                cA[r] = fg * cA[r] + ig * gg;
                hv[r] = og * tanh_fast(cA[r]);
            }
            uint2 pv; pv.x = packf2(hv[0], hv[1]); pv.y = packf2(hv[2], hv[3]);
            u32* dst = hbuf + ((size_t)(gA * 2 + par2) * BPG + lm) * 128
                            + member * 32 + w * 8 + lq * 2;
            *(uint2*)dst = pv;
            if (t >= ILEN) {
                u32* hs = (u32*)(Hs + ((size_t)(gA * 16 + lm) * TLEN + (t - ILEN)) * HDIM)
                          + member * 32 + w * 8 + lq * 2;
                *(uint2*)hs = pv;
            }
        }
        if (l == 0)
            __hip_atomic_store(&flags[fA], (u32)(t + 1), __ATOMIC_RELEASE, __HIP_MEMORY_SCOPE_AGENT);
        {
            float hv[4];
            #pragma unroll
            for (int r = 0; r < 4; ++r) {
                float ig = sigm(accB[0][r]);
                float fg = sigm(accB[1][r]);
                float gg = tanh_fast(accB[2][r]);
                float og = sigm(accB[3][r]);
                cB[r] = fg * cB[r] + ig * gg;
                hv[r] = og * tanh_fast(cB[r]);
            }
            uint2 pv; pv.x = packf2(hv[0], hv[1]); pv.y = packf2(hv[2], hv[3]);
            u32* dst = hbuf + ((size_t)(gB * 2 + par2) * BPG + lm) * 128
                            + member * 32 + w * 8 + lq * 2;
            *(uint2*)dst = pv;
            if (t >= ILEN) {
                u32* hs = (u32*)(Hs + ((size_t)(gB * 16 + lm) * TLEN + (t - ILEN)) * HDIM)
                          + member * 32 + w * 8 + lq * 2;
                *(uint2*)hs = pv;
            }
        }
        if (l == 0)
            __hip_atomic_store(&flags[fB], (u32)(t + 1), __ATOMIC_RELEASE, __HIP_MEMORY_SCOPE_AGENT);
    }
}

// ---------------------------------------------------------------------------
// Classifier: out[b][t][n] = clf_b[n] + clf_w[n]·h[b][t]. (unchanged)
// ---------------------------------------------------------------------------
#define CTT 16
__global__ __launch_bounds__(256) void clf_kernel(
    const uint4* __restrict__ Wcq,
    const __half* __restrict__ Hs,
    const float* __restrict__ clf_b,
    float* __restrict__ out)
{
    __shared__ alignas(16) u32 h_sh[CTT * (HDIM / 2)];   // 8 KB
    const int tid = threadIdx.x;
    const int b  = blockIdx.x >> 6;
    const int t0 = (blockIdx.x & 63) * CTT;

    const uint4* hsrc = (const uint4*)(Hs + ((size_t)b * TLEN + t0) * HDIM);
    uint4* hdst = (uint4*)h_sh;
    hdst[tid]       = hsrc[tid];
    hdst[tid + 256] = hsrc[tid + 256];
    __syncthreads();

    const int n  = tid & (NCLS - 1);
    const int tl = tid >> 7;
    const float bias = clf_b[n];
    float acc[8];
    #pragma unroll
    for (int q = 0; q < 8; ++q) acc[q] = bias;

    #pragma unroll 4
    for (int k4 = 0; k4 < HDIM / 8; ++k4) {
        uint4 w = Wcq[k4 * NCLS + n];
        #pragma unroll
        for (int q = 0; q < 8; ++q) {
            const uint4* hp = (const uint4*)(h_sh + (tl + 2 * q) * (HDIM / 2));
            uint4 h = hp[k4];
            acc[q] = fdot2(w.x, h.x, acc[q]);
            acc[q] = fdot2(w.y, h.y, acc[q]);
            acc[q] = fdot2(w.z, h.z, acc[q]);
            acc[q] = fdot2(w.w, h.w, acc[q]);
        }
    }
    #pragma unroll
    for (int q = 0; q < 8; ++q) {
        out[((size_t)b * TLEN + t0 + tl + 2 * q) * NCLS + n] = acc[q];
    }
}

// ---------------------------------------------------------------------------
extern "C" void kernel_launch(void* const* d_in, const int* in_sizes, int n_in,
                              void* d_out, int out_size, void* d_ws, size_t ws_size,
                              hipStream_t stream)
{
    const float* inp   = (const float*)d_in[0];
    // d_in[1] = tlen (1024, hardcoded)
    const float* w_ih  = (const float*)d_in[2];
    const float* w_hh  = (const float*)d_in[3];
    const float* bias  = (const float*)d_in[4];
    const float* clf_w = (const float*)d_in[5];
    const float* clf_b = (const float*)d_in[6];
    float* out = (float*)d_out;

    char* ws = (char*)d_ws;
    uint4*  Apack  = (uint4*)(ws);                    // 512 KB
    uint4*  Aipack = (uint4*)(ws + 524288);           // 256 KB
    uint4*  Wcq    = (uint4*)(ws + 786432);           // 64 KB
    __half* Hs     = (__half*)(ws + 851968);          // 33.55 MB
    u32*    hbuf   = (u32*)(ws + 34406400);           // 64 KB
    u32*    flags  = (u32*)(ws + 34471936);           // 256 B

    init_kernel<<<64, 256, 0, stream>>>(hbuf, flags);
    pack_kernel<<<208, 256, 0, stream>>>(w_ih, w_hh, clf_w, Apack, Aipack, Wcq);

    void* args[] = {(void*)&inp, (void*)&bias, (void*)&Apack, (void*)&Aipack,
                    (void*)&Hs, (void*)&hbuf, (void*)&flags};
    hipLaunchCooperativeKernel((const void*)lstm_rec,
                               dim3(NMEM * 2), dim3(256), args, 0, stream);

    clf_kernel<<<BSZ * (TLEN / CTT), 256, 0, stream>>>(Wcq, Hs, clf_b, out);
}

// Round 9
// 13797.508 us; speedup vs baseline: 1.2813x; 1.2813x over previous
//
#include <hip/hip_runtime.h>
#include <hip/hip_fp16.h>

#define BSZ   64
#define ILEN  1024
#define TLEN  1024
#define TTOT  2048
#define IDIM  128
#define HDIM  256
#define GDIM  1024   // 4*HDIM
#define NCLS  128
#define NGRP  8      // batch groups (one per XCD)
#define NMEM  4      // member blocks per group (64 units each)
#define BPG   8      // batches per group

typedef unsigned int u32;
typedef _Float16 f16x8 __attribute__((ext_vector_type(8)));
typedef float f32x4 __attribute__((ext_vector_type(4)));
typedef _Float16 h2_t __attribute__((ext_vector_type(2)));

union U4H8 { uint4 u; f16x8 h; };

__device__ __forceinline__ float fdot2(u32 a, u32 b, float acc) {
#if __has_builtin(__builtin_amdgcn_fdot2)
    union { u32 u; h2_t h; } ua, ub;
    ua.u = a; ub.u = b;
    return __builtin_amdgcn_fdot2(ua.h, ub.h, acc, false);
#else
    union { u32 u; __half2 h; } ua, ub;
    ua.u = a; ub.u = b;
    return acc + __low2float(ua.h) * __low2float(ub.h)
               + __high2float(ua.h) * __high2float(ub.h);
#endif
}

__device__ __forceinline__ u32 packf2(float x, float y) {
    __half2 h = __floats2half2_rn(x, y);
    union { __half2 h; u32 u; } c; c.h = h;
    return c.u;
}

__device__ __forceinline__ float sigm(float x) { return 1.f / (1.f + __expf(-x)); }
__device__ __forceinline__ float tanh_fast(float x) { return 1.f - 2.f / (__expf(2.f * x) + 1.f); }

// ---------------------------------------------------------------------------
// Pack weights into MFMA A-fragment order (f16). (Layouts verified by R6-R8
// passing absmax.)
//  Apack  (w_hh): chunk ci = ug*32 + g*8 + kt, lane l, j holds
//       w_hh[g*256 + ug*16 + (l&15)][kt*32 + (l>>4)*8 + j]
//  Aipack (w_ih): chunk ci = ug*16 + g*4 + kt4, same row, K = kt4*32+(l>>4)*8+j
//  Wcq    (clf):  [k4][n] uint4 layout for clf_kernel
// ---------------------------------------------------------------------------
__global__ void pack_kernel(const float* __restrict__ w_ih,
                            const float* __restrict__ w_hh,
                            const float* __restrict__ clf_w,
                            uint4* __restrict__ Apack,
                            uint4* __restrict__ Aipack,
                            uint4* __restrict__ Wcq)
{
    int i = blockIdx.x * blockDim.x + threadIdx.x;
    if (i < 32768) {                       // Apack: 512 chunks x 64 lanes
        int ci = i >> 6, l = i & 63;
        int ug = ci >> 5, g = (ci >> 3) & 3, kt = ci & 7;
        int R  = g * HDIM + ug * 16 + (l & 15);
        int K0 = kt * 32 + (l >> 4) * 8;
        const float* src = w_hh + (size_t)R * HDIM + K0;
        uint4 v;
        v.x = packf2(src[0], src[1]); v.y = packf2(src[2], src[3]);
        v.z = packf2(src[4], src[5]); v.w = packf2(src[6], src[7]);
        Apack[i] = v;
    } else if (i < 49152) {                // Aipack: 256 chunks x 64 lanes
        int r = i - 32768;
        int ci = r >> 6, l = r & 63;
        int ug = ci >> 4, g = (ci >> 2) & 3, kt4 = ci & 3;
        int R  = g * HDIM + ug * 16 + (l & 15);
        int K0 = kt4 * 32 + (l >> 4) * 8;
        const float* src = w_ih + (size_t)R * IDIM + K0;
        uint4 v;
        v.x = packf2(src[0], src[1]); v.y = packf2(src[2], src[3]);
        v.z = packf2(src[4], src[5]); v.w = packf2(src[6], src[7]);
        Aipack[r] = v;
    } else if (i < 53248) {                // Wcq (clf)
        int r = i - 49152;
        int n = r & (NCLS - 1);
        int k4 = r >> 7;
        const float* src = clf_w + (size_t)n * HDIM + k4 * 8;
        uint4 v;
        v.x = packf2(src[0], src[1]); v.y = packf2(src[2], src[3]);
        v.z = packf2(src[4], src[5]); v.w = packf2(src[6], src[7]);
        Wcq[r] = v;
    }
}

// ---------------------------------------------------------------------------
// Zero h-exchange buffers and flags every launch (ws poisoned 0xAA once;
// timing replays don't re-poison; flags must start at 0, h at exact 0).
// ---------------------------------------------------------------------------
__global__ void init_kernel(u32* __restrict__ hbuf, u32* __restrict__ flags)
{
    int i = blockIdx.x * blockDim.x + threadIdx.x;
    if (i < NGRP * 2 * BPG * 128) hbuf[i] = 0u;
    if (i < NGRP * 16) flags[i] = 0u;
}

// ---------------------------------------------------------------------------
// MFMA recurrent kernel, barrier-free inner loop, 32 blocks.
// Group g (8 batches) = blocks {g, g+8, g+16, g+24} -> ALL on XCD g under
// round-robin dispatch (same-XCD sync + shared-L2 x reads, proven in R7).
// member = blk>>3 owns units [member*64,+64); wave w owns 16 units x all 4
// gates => in-register epilogue (proven R8), NO __syncthreads in t-loop.
// Flags: one slot per wave, release store after hbuf publish; consumers
// acquire-poll then plain dwordx4 h loads. B-tile cols 8-15 duplicate 0-7.
// ---------------------------------------------------------------------------
__global__ __launch_bounds__(256, 1) void lstm_rec(
    const float* __restrict__ inp,
    const float* __restrict__ bias_g,
    const uint4* __restrict__ Apack,
    const uint4* __restrict__ Aipack,
    __half* __restrict__ Hs,
    u32* __restrict__ hbuf,     // [NGRP][2][BPG][128] u32 (f16 pairs [b][u/2])
    u32* __restrict__ flags)    // [NGRP][16] slot = member*4 + wave
{
    __shared__ alignas(16) uint4 whA[128 * 64];   // 128 KB, member's w_hh

    const int blk    = blockIdx.x;     // 0..31
    const int g      = blk & 7;        // group / XCD
    const int member = blk >> 3;       // 0..3
    const int tid = threadIdx.x;
    const int w   = tid >> 6;          // wave: units [member*64+w*16, +16)
    const int l   = tid & 63;
    const int lq  = l >> 4;            // k-quarter
    const int lm  = l & 15;            // B-col (batch; 8 valid)
    const int bm  = lm & 7;            // batch within group (wrapped)

    // stage member's w_hh A-fragments (identity copy)
    {
        const uint4* src = Apack + (size_t)member * 8192;
        #pragma unroll
        for (int s = 0; s < 32; ++s) whA[s * 256 + tid] = src[s * 256 + tid];
    }
    __syncthreads();   // the only block barrier

    f32x4 biasv[4];
    #pragma unroll
    for (int gg = 0; gg < 4; ++gg) {
        const float* bp = bias_g + gg * HDIM + member * 64 + w * 16 + lq * 4;
        biasv[gg] = (f32x4){bp[0], bp[1], bp[2], bp[3]};
    }

    float cS[4] = {0.f, 0.f, 0.f, 0.f};

    const uint4* hb4 = (const uint4*)hbuf;
    u32* fl = flags + g * 16;
    const int fslot = g * 16 + member * 4 + w;
    const int fidx  = l & 15;

    for (int t = 0; t < TTOT; ++t) {
        const int par  = t & 1;
        const int par2 = (t + 1) & 1;

        // ---- flag-independent loads issued BEFORE the poll (hide under sync)
        uint4 bx[4];
        uint4 wiAr[4][4];
        if (t < ILEN) {
            const float* xr = inp + ((size_t)(g * 8 + bm) * ILEN + t) * IDIM + lq * 8;
            #pragma unroll
            for (int k4 = 0; k4 < 4; ++k4) {
                float4 a0 = *(const float4*)(xr + k4 * 32);
                float4 a1 = *(const float4*)(xr + k4 * 32 + 4);
                bx[k4].x = packf2(a0.x, a0.y); bx[k4].y = packf2(a0.z, a0.w);
                bx[k4].z = packf2(a1.x, a1.y); bx[k4].w = packf2(a1.z, a1.w);
            }
            #pragma unroll
            for (int gg = 0; gg < 4; ++gg)
                #pragma unroll
                for (int k4 = 0; k4 < 4; ++k4)
                    wiAr[gg][k4] = Aipack[((size_t)(member * 4 + w) * 16 + gg * 4 + k4) * 64 + l];
        }

        // ---- acquire-poll: all 16 producer waves of the group done step t-1
        if (t > 0) {
            while (true) {
                u32 v = __hip_atomic_load(fl + fidx, __ATOMIC_ACQUIRE,
                                          __HIP_MEMORY_SCOPE_AGENT);
                if (__all(v >= (u32)t)) break;
                __builtin_amdgcn_s_sleep(1);
            }
        }

        // ---- h B-fragments (plain dwordx4; acquire above fences staleness)
        uint4 hA[8];
        {
            const uint4* pA = hb4 + ((size_t)(g * 2 + par) * BPG + bm) * 32 + lq;
            #pragma unroll
            for (int kt = 0; kt < 8; ++kt) hA[kt] = pA[kt * 4];
        }

        // ---- MFMAs: x part first (independent of h loads), then h part
        f32x4 acc[4];
        #pragma unroll
        for (int gg = 0; gg < 4; ++gg) acc[gg] = biasv[gg];
        if (t < ILEN) {
            #pragma unroll
            for (int k4 = 0; k4 < 4; ++k4) {
                U4H8 b; b.u = bx[k4];
                #pragma unroll
                for (int gg = 0; gg < 4; ++gg) {
                    U4H8 a; a.u = wiAr[gg][k4];
                    acc[gg] = __builtin_amdgcn_mfma_f32_16x16x32_f16(a.h, b.h, acc[gg], 0, 0, 0);
                }
            }
        }
        #pragma unroll
        for (int kt = 0; kt < 8; ++kt) {
            U4H8 b; b.u = hA[kt];
            #pragma unroll
            for (int gg = 0; gg < 4; ++gg) {
                U4H8 a; a.u = whA[((w * 4 + gg) * 8 + kt) * 64 + l];
                acc[gg] = __builtin_amdgcn_mfma_f32_16x16x32_f16(a.h, b.h, acc[gg], 0, 0, 0);
            }
        }

        // ---- in-register epilogue + publish (unit = member*64+w*16+lq*4+r,
        //      batch = g*8+lm), lanes lm<8 only
        uint2 pv;
        if (lm < 8) {
            float hv[4];
            #pragma unroll
            for (int r = 0; r < 4; ++r) {
                float ig = sigm(acc[0][r]);
                float fg = sigm(acc[1][r]);
                float gg = tanh_fast(acc[2][r]);
                float og = sigm(acc[3][r]);
                cS[r] = fg * cS[r] + ig * gg;
                hv[r] = og * tanh_fast(cS[r]);
            }
            pv.x = packf2(hv[0], hv[1]); pv.y = packf2(hv[2], hv[3]);
            u32* dst = hbuf + ((size_t)(g * 2 + par2) * BPG + lm) * 128
                            + member * 32 + w * 8 + lq * 2;
            *(uint2*)dst = pv;
        }
        // release own slot: orders the hbuf publish (Hs store deferred after)
        if (l == 0)
            __hip_atomic_store(&flags[fslot], (u32)(t + 1), __ATOMIC_RELEASE,
                               __HIP_MEMORY_SCOPE_AGENT);
        if (lm < 8 && t >= ILEN) {
            u32* hs = (u32*)(Hs + ((size_t)(g * 8 + lm) * TLEN + (t - ILEN)) * HDIM)
                      + member * 32 + w * 8 + lq * 2;
            *(uint2*)hs = pv;
        }
    }
}

// ---------------------------------------------------------------------------
// Classifier: out[b][t][n] = clf_b[n] + clf_w[n]·h[b][t]. (unchanged)
// ---------------------------------------------------------------------------
#define CTT 16
__global__ __launch_bounds__(256) void clf_kernel(
    const uint4* __restrict__ Wcq,
    const __half* __restrict__ Hs,
    const float* __restrict__ clf_b,
    float* __restrict__ out)
{
    __shared__ alignas(16) u32 h_sh[CTT * (HDIM / 2)];   // 8 KB
    const int tid = threadIdx.x;
    const int b  = blockIdx.x >> 6;
    const int t0 = (blockIdx.x & 63) * CTT;

    const uint4* hsrc = (const uint4*)(Hs + ((size_t)b * TLEN + t0) * HDIM);
    uint4* hdst = (uint4*)h_sh;
    hdst[tid]       = hsrc[tid];
    hdst[tid + 256] = hsrc[tid + 256];
    __syncthreads();

    const int n  = tid & (NCLS - 1);
    const int tl = tid >> 7;
    const float bias = clf_b[n];
    float acc[8];
    #pragma unroll
    for (int q = 0; q < 8; ++q) acc[q] = bias;

    #pragma unroll 4
    for (int k4 = 0; k4 < HDIM / 8; ++k4) {
        uint4 w = Wcq[k4 * NCLS + n];
        #pragma unroll
        for (int q = 0; q < 8; ++q) {
            const uint4* hp = (const uint4*)(h_sh + (tl + 2 * q) * (HDIM / 2));
            uint4 h = hp[k4];
            acc[q] = fdot2(w.x, h.x, acc[q]);
            acc[q] = fdot2(w.y, h.y, acc[q]);
            acc[q] = fdot2(w.z, h.z, acc[q]);
            acc[q] = fdot2(w.w, h.w, acc[q]);
        }
    }
    #pragma unroll
    for (int q = 0; q < 8; ++q) {
        out[((size_t)b * TLEN + t0 + tl + 2 * q) * NCLS + n] = acc[q];
    }
}

// ---------------------------------------------------------------------------
extern "C" void kernel_launch(void* const* d_in, const int* in_sizes, int n_in,
                              void* d_out, int out_size, void* d_ws, size_t ws_size,
                              hipStream_t stream)
{
    const float* inp   = (const float*)d_in[0];
    // d_in[1] = tlen (1024, hardcoded)
    const float* w_ih  = (const float*)d_in[2];
    const float* w_hh  = (const float*)d_in[3];
    const float* bias  = (const float*)d_in[4];
    const float* clf_w = (const float*)d_in[5];
    const float* clf_b = (const float*)d_in[6];
    float* out = (float*)d_out;

    char* ws = (char*)d_ws;
    uint4*  Apack  = (uint4*)(ws);                    // 512 KB
    uint4*  Aipack = (uint4*)(ws + 524288);           // 256 KB
    uint4*  Wcq    = (uint4*)(ws + 786432);           // 64 KB
    __half* Hs     = (__half*)(ws + 851968);          // 33.55 MB
    u32*    hbuf   = (u32*)(ws + 34406400);           // 64 KB
    u32*    flags  = (u32*)(ws + 34471936);           // 512 B

    init_kernel<<<64, 256, 0, stream>>>(hbuf, flags);
    pack_kernel<<<208, 256, 0, stream>>>(w_ih, w_hh, clf_w, Apack, Aipack, Wcq);

    void* args[] = {(void*)&inp, (void*)&bias, (void*)&Apack, (void*)&Aipack,
                    (void*)&Hs, (void*)&hbuf, (void*)&flags};
    hipLaunchCooperativeKernel((const void*)lstm_rec,
                               dim3(NGRP * NMEM), dim3(256), args, 0, stream);

    clf_kernel<<<BSZ * (TLEN / CTT), 256, 0, stream>>>(Wcq, Hs, clf_b, out);
}

// Round 10
// 13187.035 us; speedup vs baseline: 1.3406x; 1.0463x over previous
//
#include <hip/hip_runtime.h>
#include <hip/hip_fp16.h>

#define BSZ   64
#define ILEN  1024
#define TLEN  1024
#define TTOT  2048
#define IDIM  128
#define HDIM  256
#define GDIM  1024   // 4*HDIM
#define NCLS  128
#define NGRP  8      // batch groups (one per XCD)
#define NMEM  4      // member blocks per group (64 units each)
#define BPG   8      // batches per group

typedef unsigned int u32;
typedef _Float16 f16x8 __attribute__((ext_vector_type(8)));
typedef float f32x4 __attribute__((ext_vector_type(4)));
typedef _Float16 h2_t __attribute__((ext_vector_type(2)));

union U4H8 { uint4 u; f16x8 h; };

__device__ __forceinline__ float fdot2(u32 a, u32 b, float acc) {
#if __has_builtin(__builtin_amdgcn_fdot2)
    union { u32 u; h2_t h; } ua, ub;
    ua.u = a; ub.u = b;
    return __builtin_amdgcn_fdot2(ua.h, ub.h, acc, false);
#else
    union { u32 u; __half2 h; } ua, ub;
    ua.u = a; ub.u = b;
    return acc + __low2float(ua.h) * __low2float(ub.h)
               + __high2float(ua.h) * __high2float(ub.h);
#endif
}

__device__ __forceinline__ u32 packf2(float x, float y) {
    __half2 h = __floats2half2_rn(x, y);
    union { __half2 h; u32 u; } c; c.h = h;
    return c.u;
}

__device__ __forceinline__ float sigm(float x) { return 1.f / (1.f + __expf(-x)); }
__device__ __forceinline__ float tanh_fast(float x) { return 1.f - 2.f / (__expf(2.f * x) + 1.f); }

// ---------------------------------------------------------------------------
// Pack weights into MFMA A-fragment order (f16). (Layouts verified R6-R9.)
//  Apack  (w_hh): chunk ci = ug*32 + g*8 + kt, lane l, j holds
//       w_hh[g*256 + ug*16 + (l&15)][kt*32 + (l>>4)*8 + j]
//  Aipack (w_ih): chunk ci = ug*16 + g*4 + kt4, same row, K = kt4*32+(l>>4)*8+j
//  Wcq    (clf):  [k4][n] uint4 layout for clf_kernel
// ---------------------------------------------------------------------------
__global__ void pack_kernel(const float* __restrict__ w_ih,
                            const float* __restrict__ w_hh,
                            const float* __restrict__ clf_w,
                            uint4* __restrict__ Apack,
                            uint4* __restrict__ Aipack,
                            uint4* __restrict__ Wcq)
{
    int i = blockIdx.x * blockDim.x + threadIdx.x;
    if (i < 32768) {                       // Apack: 512 chunks x 64 lanes
        int ci = i >> 6, l = i & 63;
        int ug = ci >> 5, g = (ci >> 3) & 3, kt = ci & 7;
        int R  = g * HDIM + ug * 16 + (l & 15);
        int K0 = kt * 32 + (l >> 4) * 8;
        const float* src = w_hh + (size_t)R * HDIM + K0;
        uint4 v;
        v.x = packf2(src[0], src[1]); v.y = packf2(src[2], src[3]);
        v.z = packf2(src[4], src[5]); v.w = packf2(src[6], src[7]);
        Apack[i] = v;
    } else if (i < 49152) {                // Aipack: 256 chunks x 64 lanes
        int r = i - 32768;
        int ci = r >> 6, l = r & 63;
        int ug = ci >> 4, g = (ci >> 2) & 3, kt4 = ci & 3;
        int R  = g * HDIM + ug * 16 + (l & 15);
        int K0 = kt4 * 32 + (l >> 4) * 8;
        const float* src = w_ih + (size_t)R * IDIM + K0;
        uint4 v;
        v.x = packf2(src[0], src[1]); v.y = packf2(src[2], src[3]);
        v.z = packf2(src[4], src[5]); v.w = packf2(src[6], src[7]);
        Aipack[r] = v;
    } else if (i < 53248) {                // Wcq (clf)
        int r = i - 49152;
        int n = r & (NCLS - 1);
        int k4 = r >> 7;
        const float* src = clf_w + (size_t)n * HDIM + k4 * 8;
        uint4 v;
        v.x = packf2(src[0], src[1]); v.y = packf2(src[2], src[3]);
        v.z = packf2(src[4], src[5]); v.w = packf2(src[6], src[7]);
        Wcq[r] = v;
    }
}

// ---------------------------------------------------------------------------
// Zero h-exchange buffers and flags every launch (ws poisoned 0xAA once;
// timing replays don't re-poison; flags must start at 0, h at exact 0).
// ---------------------------------------------------------------------------
__global__ void init_kernel(u32* __restrict__ hbuf, u32* __restrict__ flags)
{
    int i = blockIdx.x * blockDim.x + threadIdx.x;
    if (i < NGRP * 2 * BPG * 128) hbuf[i] = 0u;
    if (i < NGRP * 64) flags[i] = 0u;
}

// ---------------------------------------------------------------------------
// MFMA recurrent kernel, barrier-free inner loop, 32 blocks.
// Group g (8 batches) = blocks {g, g+8, g+16, g+24} -> all on XCD g
// (round-robin dispatch, FETCH-verified in R7/R9). member = blk>>3 owns
// units [member*64,+64); wave w owns 16 units x all 4 gates => in-register
// epilogue, no __syncthreads in the t-loop.
// Sync (NEW): flags[g][member][w] with one 64B LINE PER MEMBER-CU (single-
// writer lines, no write-write ping-pong). Consumers spin on RELAXED atomic
// loads (L2-direct, no per-iter drain/inv) + ONE acquire fence on exit.
// ---------------------------------------------------------------------------
__global__ __launch_bounds__(256, 1) void lstm_rec(
    const float* __restrict__ inp,
    const float* __restrict__ bias_g,
    const uint4* __restrict__ Apack,
    const uint4* __restrict__ Aipack,
    __half* __restrict__ Hs,
    u32* __restrict__ hbuf,     // [NGRP][2][BPG][128] u32 (f16 pairs [b][u/2])
    u32* __restrict__ flags)    // [NGRP][NMEM][16] u32: line per member
{
    __shared__ alignas(16) uint4 whA[128 * 64];   // 128 KB, member's w_hh

    const int blk    = blockIdx.x;     // 0..31
    const int g      = blk & 7;        // group / XCD
    const int member = blk >> 3;       // 0..3
    const int tid = threadIdx.x;
    const int w   = tid >> 6;          // wave: units [member*64+w*16, +16)
    const int l   = tid & 63;
    const int lq  = l >> 4;            // k-quarter
    const int lm  = l & 15;            // B-col (batch; 8 valid)
    const int bm  = lm & 7;            // batch within group (wrapped)

    // stage member's w_hh A-fragments (identity copy)
    {
        const uint4* src = Apack + (size_t)member * 8192;
        #pragma unroll
        for (int s = 0; s < 32; ++s) whA[s * 256 + tid] = src[s * 256 + tid];
    }
    __syncthreads();   // the only block barrier

    f32x4 biasv[4];
    #pragma unroll
    for (int gg = 0; gg < 4; ++gg) {
        const float* bp = bias_g + gg * HDIM + member * 64 + w * 16 + lq * 4;
        biasv[gg] = (f32x4){bp[0], bp[1], bp[2], bp[3]};
    }

    float cS[4] = {0.f, 0.f, 0.f, 0.f};

    const uint4* hb4 = (const uint4*)hbuf;
    u32* fl = flags + g * 64;                         // group's 4 lines
    const int fslot = g * 64 + member * 16 + w;       // own slot (own CU line)
    const int fidx  = ((l & 15) >> 2) * 16 + (l & 3); // lanes 0-15 cover 16 slots

    for (int t = 0; t < TTOT; ++t) {
        const int par  = t & 1;
        const int par2 = (t + 1) & 1;

        // ---- flag-independent loads issued BEFORE the poll (fill the wait)
        uint4 bx[4];
        uint4 wiAr[4][4];
        if (t < ILEN) {
            const float* xr = inp + ((size_t)(g * 8 + bm) * ILEN + t) * IDIM + lq * 8;
            #pragma unroll
            for (int k4 = 0; k4 < 4; ++k4) {
                float4 a0 = *(const float4*)(xr + k4 * 32);
                float4 a1 = *(const float4*)(xr + k4 * 32 + 4);
                bx[k4].x = packf2(a0.x, a0.y); bx[k4].y = packf2(a0.z, a0.w);
                bx[k4].z = packf2(a1.x, a1.y); bx[k4].w = packf2(a1.z, a1.w);
            }
            #pragma unroll
            for (int gg = 0; gg < 4; ++gg)
                #pragma unroll
                for (int k4 = 0; k4 < 4; ++k4)
                    wiAr[gg][k4] = Aipack[((size_t)(member * 4 + w) * 16 + gg * 4 + k4) * 64 + l];
        }

        // ---- poll: relaxed spins (no drain/inv per iter), one acquire fence
        if (t > 0) {
            while (true) {
                u32 v = __hip_atomic_load(fl + fidx, __ATOMIC_RELAXED,
                                          __HIP_MEMORY_SCOPE_AGENT);
                if (__all(v >= (u32)t)) break;
                __builtin_amdgcn_s_sleep(1);
            }
            __builtin_amdgcn_fence(__ATOMIC_ACQUIRE, "agent");
        }

        // ---- h B-fragments (plain dwordx4; fence above guarantees fresh L2)
        uint4 hA[8];
        {
            const uint4* pA = hb4 + ((size_t)(g * 2 + par) * BPG + bm) * 32 + lq;
            #pragma unroll
            for (int kt = 0; kt < 8; ++kt) hA[kt] = pA[kt * 4];
        }

        // ---- MFMAs: x part first (operands already in regs), then h part
        f32x4 acc[4];
        #pragma unroll
        for (int gg = 0; gg < 4; ++gg) acc[gg] = biasv[gg];
        if (t < ILEN) {
            #pragma unroll
            for (int k4 = 0; k4 < 4; ++k4) {
                U4H8 b; b.u = bx[k4];
                #pragma unroll
                for (int gg = 0; gg < 4; ++gg) {
                    U4H8 a; a.u = wiAr[gg][k4];
                    acc[gg] = __builtin_amdgcn_mfma_f32_16x16x32_f16(a.h, b.h, acc[gg], 0, 0, 0);
                }
            }
        }
        #pragma unroll
        for (int kt = 0; kt < 8; ++kt) {
            U4H8 b; b.u = hA[kt];
            #pragma unroll
            for (int gg = 0; gg < 4; ++gg) {
                U4H8 a; a.u = whA[((w * 4 + gg) * 8 + kt) * 64 + l];
                acc[gg] = __builtin_amdgcn_mfma_f32_16x16x32_f16(a.h, b.h, acc[gg], 0, 0, 0);
            }
        }

        // ---- in-register epilogue + publish (unit = member*64+w*16+lq*4+r,
        //      batch = g*8+lm), lanes lm<8 only
        uint2 pv;
        if (lm < 8) {
            float hv[4];
            #pragma unroll
            for (int r = 0; r < 4; ++r) {
                float ig = sigm(acc[0][r]);
                float fg = sigm(acc[1][r]);
                float gg = tanh_fast(acc[2][r]);
                float og = sigm(acc[3][r]);
                cS[r] = fg * cS[r] + ig * gg;
                hv[r] = og * tanh_fast(cS[r]);
            }
            pv.x = packf2(hv[0], hv[1]); pv.y = packf2(hv[2], hv[3]);
            u32* dst = hbuf + ((size_t)(g * 2 + par2) * BPG + lm) * 128
                            + member * 32 + w * 8 + lq * 2;
            *(uint2*)dst = pv;
        }
        // release own slot (single-writer line): orders the hbuf publish
        if (l == 0)
            __hip_atomic_store(&flags[fslot], (u32)(t + 1), __ATOMIC_RELEASE,
                               __HIP_MEMORY_SCOPE_AGENT);
        if (lm < 8 && t >= ILEN) {
            u32* hs = (u32*)(Hs + ((size_t)(g * 8 + lm) * TLEN + (t - ILEN)) * HDIM)
                      + member * 32 + w * 8 + lq * 2;
            *(uint2*)hs = pv;
        }
    }
}

// ---------------------------------------------------------------------------
// Classifier: out[b][t][n] = clf_b[n] + clf_w[n]·h[b][t]. (unchanged)
// ---------------------------------------------------------------------------
#define CTT 16
__global__ __launch_bounds__(256) void clf_kernel(
    const uint4* __restrict__ Wcq,
    const __half* __restrict__ Hs,
    const float* __restrict__ clf_b,
    float* __restrict__ out)
{
    __shared__ alignas(16) u32 h_sh[CTT * (HDIM / 2)];   // 8 KB
    const int tid = threadIdx.x;
    const int b  = blockIdx.x >> 6;
    const int t0 = (blockIdx.x & 63) * CTT;

    const uint4* hsrc = (const uint4*)(Hs + ((size_t)b * TLEN + t0) * HDIM);
    uint4* hdst = (uint4*)h_sh;
    hdst[tid]       = hsrc[tid];
    hdst[tid + 256] = hsrc[tid + 256];
    __syncthreads();

    const int n  = tid & (NCLS - 1);
    const int tl = tid >> 7;
    const float bias = clf_b[n];
    float acc[8];
    #pragma unroll
    for (int q = 0; q < 8; ++q) acc[q] = bias;

    #pragma unroll 4
    for (int k4 = 0; k4 < HDIM / 8; ++k4) {
        uint4 w = Wcq[k4 * NCLS + n];
        #pragma unroll
        for (int q = 0; q < 8; ++q) {
            const uint4* hp = (const uint4*)(h_sh + (tl + 2 * q) * (HDIM / 2));
            uint4 h = hp[k4];
            acc[q] = fdot2(w.x, h.x, acc[q]);
            acc[q] = fdot2(w.y, h.y, acc[q]);
            acc[q] = fdot2(w.z, h.z, acc[q]);
            acc[q] = fdot2(w.w, h.w, acc[q]);
        }
    }
    #pragma unroll
    for (int q = 0; q < 8; ++q) {
        out[((size_t)b * TLEN + t0 + tl + 2 * q) * NCLS + n] = acc[q];
    }
}

// ---------------------------------------------------------------------------
extern "C" void kernel_launch(void* const* d_in, const int* in_sizes, int n_in,
                              void* d_out, int out_size, void* d_ws, size_t ws_size,
                              hipStream_t stream)
{
    const float* inp   = (const float*)d_in[0];
    // d_in[1] = tlen (1024, hardcoded)
    const float* w_ih  = (const float*)d_in[2];
    const float* w_hh  = (const float*)d_in[3];
    const float* bias  = (const float*)d_in[4];
    const float* clf_w = (const float*)d_in[5];
    const float* clf_b = (const float*)d_in[6];
    float* out = (float*)d_out;

    char* ws = (char*)d_ws;
    uint4*  Apack  = (uint4*)(ws);                    // 512 KB
    uint4*  Aipack = (uint4*)(ws + 524288);           // 256 KB
    uint4*  Wcq    = (uint4*)(ws + 786432);           // 64 KB
    __half* Hs     = (__half*)(ws + 851968);          // 33.55 MB
    u32*    hbuf   = (u32*)(ws + 34406400);           // 64 KB
    u32*    flags  = (u32*)(ws + 34471936);           // 2 KB

    init_kernel<<<64, 256, 0, stream>>>(hbuf, flags);
    pack_kernel<<<208, 256, 0, stream>>>(w_ih, w_hh, clf_w, Apack, Aipack, Wcq);

    void* args[] = {(void*)&inp, (void*)&bias, (void*)&Apack, (void*)&Aipack,
                    (void*)&Hs, (void*)&hbuf, (void*)&flags};
    hipLaunchCooperativeKernel((const void*)lstm_rec,
                               dim3(NGRP * NMEM), dim3(256), args, 0, stream);

    clf_kernel<<<BSZ * (TLEN / CTT), 256, 0, stream>>>(Wcq, Hs, clf_b, out);
}

// Round 12
// 8683.008 us; speedup vs baseline: 2.0360x; 1.5187x over previous
//
#include <hip/hip_runtime.h>
#include <hip/hip_fp16.h>

#define BSZ   64
#define ILEN  1024
#define TLEN  1024
#define TTOT  2048
#define IDIM  128
#define HDIM  256
#define GDIM  1024   // 4*HDIM
#define NCLS  128
#define NGRP  8      // batch groups
#define NMEM  4      // member blocks per group (64 units each)
#define BPG   8      // batches per group

typedef unsigned int u32;
typedef _Float16 f16x8 __attribute__((ext_vector_type(8)));
typedef float f32x4 __attribute__((ext_vector_type(4)));
typedef _Float16 h2_t __attribute__((ext_vector_type(2)));

union U4H8 { uint4 u; f16x8 h; };

__device__ __forceinline__ float fdot2(u32 a, u32 b, float acc) {
#if __has_builtin(__builtin_amdgcn_fdot2)
    union { u32 u; h2_t h; } ua, ub;
    ua.u = a; ub.u = b;
    return __builtin_amdgcn_fdot2(ua.h, ub.h, acc, false);
#else
    union { u32 u; __half2 h; } ua, ub;
    ua.u = a; ub.u = b;
    return acc + __low2float(ua.h) * __low2float(ub.h)
               + __high2float(ua.h) * __high2float(ub.h);
#endif
}

__device__ __forceinline__ u32 packf2(float x, float y) {
    __half2 h = __floats2half2_rn(x, y);
    union { __half2 h; u32 u; } c; c.h = h;
    return c.u;
}

__device__ __forceinline__ float sigm(float x) { return 1.f / (1.f + __expf(-x)); }
__device__ __forceinline__ float tanh_fast(float x) { return 1.f - 2.f / (__expf(2.f * x) + 1.f); }

// ---------------------------------------------------------------------------
// Pack weights into MFMA A-fragment order (f16). (Layouts verified R6-R10.)
// ---------------------------------------------------------------------------
__global__ void pack_kernel(const float* __restrict__ w_ih,
                            const float* __restrict__ w_hh,
                            const float* __restrict__ clf_w,
                            uint4* __restrict__ Apack,
                            uint4* __restrict__ Aipack,
                            uint4* __restrict__ Wcq)
{
    int i = blockIdx.x * blockDim.x + threadIdx.x;
    if (i < 32768) {                       // Apack: 512 chunks x 64 lanes
        int ci = i >> 6, l = i & 63;
        int ug = ci >> 5, g = (ci >> 3) & 3, kt = ci & 7;
        int R  = g * HDIM + ug * 16 + (l & 15);
        int K0 = kt * 32 + (l >> 4) * 8;
        const float* src = w_hh + (size_t)R * HDIM + K0;
        uint4 v;
        v.x = packf2(src[0], src[1]); v.y = packf2(src[2], src[3]);
        v.z = packf2(src[4], src[5]); v.w = packf2(src[6], src[7]);
        Apack[i] = v;
    } else if (i < 49152) {                // Aipack: 256 chunks x 64 lanes
        int r = i - 32768;
        int ci = r >> 6, l = r & 63;
        int ug = ci >> 4, g = (ci >> 2) & 3, kt4 = ci & 3;
        int R  = g * HDIM + ug * 16 + (l & 15);
        int K0 = kt4 * 32 + (l >> 4) * 8;
        const float* src = w_ih + (size_t)R * IDIM + K0;
        uint4 v;
        v.x = packf2(src[0], src[1]); v.y = packf2(src[2], src[3]);
        v.z = packf2(src[4], src[5]); v.w = packf2(src[6], src[7]);
        Aipack[r] = v;
    } else if (i < 53248) {                // Wcq (clf)
        int r = i - 49152;
        int n = r & (NCLS - 1);
        int k4 = r >> 7;
        const float* src = clf_w + (size_t)n * HDIM + k4 * 8;
        uint4 v;
        v.x = packf2(src[0], src[1]); v.y = packf2(src[2], src[3]);
        v.z = packf2(src[4], src[5]); v.w = packf2(src[6], src[7]);
        Wcq[r] = v;
    }
}

// ---------------------------------------------------------------------------
// Zero the flags every launch (ws poisoned 0xAA once; replays don't
// re-poison; flags must start at 0). hbuf needs NO init: at t=0 the poll
// and h-MFMAs are skipped (h_0 = 0), so every hbuf slot is written at step
// t before it is first read at step t+1.
// ---------------------------------------------------------------------------
__global__ void init_kernel(u32* __restrict__ flags)
{
    int i = blockIdx.x * blockDim.x + threadIdx.x;
    if (i < NGRP * 64) flags[i] = 0u;
}

// ---------------------------------------------------------------------------
// MFMA recurrent kernel, 32 blocks. Group g = blocks {g,g+8,g+16,g+24}
// (same XCD under round-robin -> fast; correctness does NOT depend on it:
// all cross-block traffic is agent-scope atomics).
// member owns units [member*64,+64); wave w owns 16 units x all 4 gates
// (in-register epilogue). Per step:
//   prefetch x/w_ih -> x-MFMAs -> relaxed poll + ONE acquire fence ->
//   stage h (4 KB, 4 agent u32 loads/thread) -> barrier -> h-MFMAs ->
//   in-reg epilogue -> publish (2 agent u32 stores) -> barrier (vmcnt
//   drain) -> tid0 release-stores member flag (single-writer 64B line).
// ---------------------------------------------------------------------------
__global__ __launch_bounds__(256, 1) void lstm_rec(
    const float* __restrict__ inp,
    const float* __restrict__ bias_g,
    const uint4* __restrict__ Apack,
    const uint4* __restrict__ Aipack,
    __half* __restrict__ Hs,
    u32* __restrict__ hbuf,     // [NGRP][2][BPG][128] u32 (f16 pairs [b][u/2])
    u32* __restrict__ flags)    // [NGRP][NMEM][16]: one 64B line per member
{
    __shared__ alignas(16) uint4 whA[128 * 64];   // 128 KB, member's w_hh
    __shared__ alignas(16) u32 hB[8 * 132];       // 4.1 KB, padded rows (33 uint4)

    const int blk    = blockIdx.x;     // 0..31
    const int g      = blk & 7;        // group
    const int member = blk >> 3;       // 0..3
    const int tid = threadIdx.x;
    const int w   = tid >> 6;          // wave: units [member*64+w*16, +16)
    const int l   = tid & 63;
    const int lq  = l >> 4;            // k-quarter
    const int lm  = l & 15;            // B-col (batch; 8 valid)
    const int bm  = lm & 7;            // batch within group (wrapped)

    // stage member's w_hh A-fragments (identity copy)
    {
        const uint4* src = Apack + (size_t)member * 8192;
        #pragma unroll
        for (int s = 0; s < 32; ++s) whA[s * 256 + tid] = src[s * 256 + tid];
    }

    f32x4 biasv[4];
    #pragma unroll
    for (int gg = 0; gg < 4; ++gg) {
        const float* bp = bias_g + gg * HDIM + member * 64 + w * 16 + lq * 4;
        biasv[gg] = (f32x4){bp[0], bp[1], bp[2], bp[3]};
    }

    float cS[4] = {0.f, 0.f, 0.f, 0.f};

    const uint4* hB4 = (const uint4*)hB;
    u32* fl = flags + g * 64;                    // 4 single-writer lines
    const int fslot = g * 64 + member * 16;      // own line, slot 0
    const int fidx  = (l & 3) * 16;              // poll 4 lines, 16-way dup
    const int hstr  = tid >> 5;                  // h-stage row 0..7
    const int hstc  = (tid & 31) * 4;            // h-stage u32 col

    __syncthreads();   // whA staged

    for (int t = 0; t < TTOT; ++t) {
        const int par  = t & 1;
        const int par2 = (t + 1) & 1;

        // ---- flag-independent loads issued BEFORE the poll
        uint4 bx[4];
        uint4 wiAr[4][4];
        if (t < ILEN) {
            const float* xr = inp + ((size_t)(g * 8 + bm) * ILEN + t) * IDIM + lq * 8;
            #pragma unroll
            for (int k4 = 0; k4 < 4; ++k4) {
                float4 a0 = *(const float4*)(xr + k4 * 32);
                float4 a1 = *(const float4*)(xr + k4 * 32 + 4);
                bx[k4].x = packf2(a0.x, a0.y); bx[k4].y = packf2(a0.z, a0.w);
                bx[k4].z = packf2(a1.x, a1.y); bx[k4].w = packf2(a1.z, a1.w);
            }
            #pragma unroll
            for (int gg = 0; gg < 4; ++gg)
                #pragma unroll
                for (int k4 = 0; k4 < 4; ++k4)
                    wiAr[gg][k4] = Aipack[((size_t)(member * 4 + w) * 16 + gg * 4 + k4) * 64 + l];
        }

        // ---- x-MFMAs (independent of h) BEFORE the poll
        f32x4 acc[4];
        #pragma unroll
        for (int gg = 0; gg < 4; ++gg) acc[gg] = biasv[gg];
        if (t < ILEN) {
            #pragma unroll
            for (int k4 = 0; k4 < 4; ++k4) {
                U4H8 b; b.u = bx[k4];
                #pragma unroll
                for (int gg = 0; gg < 4; ++gg) {
                    U4H8 a; a.u = wiAr[gg][k4];
                    acc[gg] = __builtin_amdgcn_mfma_f32_16x16x32_f16(a.h, b.h, acc[gg], 0, 0, 0);
                }
            }
        }

        if (t > 0) {
            // ---- relaxed poll (no per-iter drain/inv), then ONE acquire fence
            while (true) {
                u32 v = __hip_atomic_load(fl + fidx, __ATOMIC_RELAXED,
                                          __HIP_MEMORY_SCOPE_AGENT);
                if (__all(v >= (u32)t)) break;
                __builtin_amdgcn_s_sleep(1);
            }
            __builtin_amdgcn_fence(__ATOMIC_ACQUIRE, "agent");

            // ---- stage h (4 KB total): 4 agent u32 loads per thread -> LDS
            {
                const u32* hr = hbuf + ((size_t)(g * 2 + par) * BPG + hstr) * 128 + hstc;
                u32 v0 = __hip_atomic_load(hr + 0, __ATOMIC_RELAXED, __HIP_MEMORY_SCOPE_AGENT);
                u32 v1 = __hip_atomic_load(hr + 1, __ATOMIC_RELAXED, __HIP_MEMORY_SCOPE_AGENT);
                u32 v2 = __hip_atomic_load(hr + 2, __ATOMIC_RELAXED, __HIP_MEMORY_SCOPE_AGENT);
                u32 v3 = __hip_atomic_load(hr + 3, __ATOMIC_RELAXED, __HIP_MEMORY_SCOPE_AGENT);
                hB[hstr * 132 + hstc + 0] = v0;
                hB[hstr * 132 + hstc + 1] = v1;
                hB[hstr * 132 + hstc + 2] = v2;
                hB[hstr * 132 + hstc + 3] = v3;
            }
            __syncthreads();   // hB ready

            // ---- h-MFMAs (A from LDS conflict-free; B broadcast, padded rows)
            #pragma unroll
            for (int kt = 0; kt < 8; ++kt) {
                U4H8 b; b.u = hB4[bm * 33 + kt * 4 + lq];
                #pragma unroll
                for (int gg = 0; gg < 4; ++gg) {
                    U4H8 a; a.u = whA[((w * 4 + gg) * 8 + kt) * 64 + l];
                    acc[gg] = __builtin_amdgcn_mfma_f32_16x16x32_f16(a.h, b.h, acc[gg], 0, 0, 0);
                }
            }
        }

        // ---- in-register epilogue + publish (unit = member*64+w*16+lq*4+r,
        //      batch = g*8+lm), lanes lm<8 only
        uint2 pv;
        if (lm < 8) {
            float hv[4];
            #pragma unroll
            for (int r = 0; r < 4; ++r) {
                float ig = sigm(acc[0][r]);
                float fg = sigm(acc[1][r]);
                float gg = tanh_fast(acc[2][r]);
                float og = sigm(acc[3][r]);
                cS[r] = fg * cS[r] + ig * gg;
                hv[r] = og * tanh_fast(cS[r]);
            }
            pv.x = packf2(hv[0], hv[1]); pv.y = packf2(hv[2], hv[3]);
            u32* dst = hbuf + ((size_t)(g * 2 + par2) * BPG + lm) * 128
                            + member * 32 + w * 8 + lq * 2;
            __hip_atomic_store(dst + 0, pv.x, __ATOMIC_RELAXED, __HIP_MEMORY_SCOPE_AGENT);
            __hip_atomic_store(dst + 1, pv.y, __ATOMIC_RELAXED, __HIP_MEMORY_SCOPE_AGENT);
        }
        // barrier drains all waves' publish stores (vmcnt0 before s_barrier),
        // then one release store raises the member flag (single-writer line)
        __syncthreads();
        if (tid == 0)
            __hip_atomic_store(&flags[fslot], (u32)(t + 1), __ATOMIC_RELEASE,
                               __HIP_MEMORY_SCOPE_AGENT);
        // history store off the critical path
        if (lm < 8 && t >= ILEN) {
            u32* hs = (u32*)(Hs + ((size_t)(g * 8 + lm) * TLEN + (t - ILEN)) * HDIM)
                      + member * 32 + w * 8 + lq * 2;
            *(uint2*)hs = pv;
        }
    }
}

// ---------------------------------------------------------------------------
// Classifier: out[b][t][n] = clf_b[n] + clf_w[n]·h[b][t]. (unchanged)
// ---------------------------------------------------------------------------
#define CTT 16
__global__ __launch_bounds__(256) void clf_kernel(
    const uint4* __restrict__ Wcq,
    const __half* __restrict__ Hs,
    const float* __restrict__ clf_b,
    float* __restrict__ out)
{
    __shared__ alignas(16) u32 h_sh[CTT * (HDIM / 2)];   // 8 KB
    const int tid = threadIdx.x;
    const int b  = blockIdx.x >> 6;
    const int t0 = (blockIdx.x & 63) * CTT;

    const uint4* hsrc = (const uint4*)(Hs + ((size_t)b * TLEN + t0) * HDIM);
    uint4* hdst = (uint4*)h_sh;
    hdst[tid]       = hsrc[tid];
    hdst[tid + 256] = hsrc[tid + 256];
    __syncthreads();

    const int n  = tid & (NCLS - 1);
    const int tl = tid >> 7;
    const float bias = clf_b[n];
    float acc[8];
    #pragma unroll
    for (int q = 0; q < 8; ++q) acc[q] = bias;

    #pragma unroll 4
    for (int k4 = 0; k4 < HDIM / 8; ++k4) {
        uint4 w = Wcq[k4 * NCLS + n];
        #pragma unroll
        for (int q = 0; q < 8; ++q) {
            const uint4* hp = (const uint4*)(h_sh + (tl + 2 * q) * (HDIM / 2));
            uint4 h = hp[k4];
            acc[q] = fdot2(w.x, h.x, acc[q]);
            acc[q] = fdot2(w.y, h.y, acc[q]);
            acc[q] = fdot2(w.z, h.z, acc[q]);
            acc[q] = fdot2(w.w, h.w, acc[q]);
        }
    }
    #pragma unroll
    for (int q = 0; q < 8; ++q) {
        out[((size_t)b * TLEN + t0 + tl + 2 * q) * NCLS + n] = acc[q];
    }
}

// ---------------------------------------------------------------------------
extern "C" void kernel_launch(void* const* d_in, const int* in_sizes, int n_in,
                              void* d_out, int out_size, void* d_ws, size_t ws_size,
                              hipStream_t stream)
{
    const float* inp   = (const float*)d_in[0];
    // d_in[1] = tlen (1024, hardcoded)
    const float* w_ih  = (const float*)d_in[2];
    const float* w_hh  = (const float*)d_in[3];
    const float* bias  = (const float*)d_in[4];
    const float* clf_w = (const float*)d_in[5];
    const float* clf_b = (const float*)d_in[6];
    float* out = (float*)d_out;

    char* ws = (char*)d_ws;
    uint4*  Apack  = (uint4*)(ws);                    // 512 KB
    uint4*  Aipack = (uint4*)(ws + 524288);           // 256 KB
    uint4*  Wcq    = (uint4*)(ws + 786432);           // 64 KB
    __half* Hs     = (__half*)(ws + 851968);          // 33.55 MB
    u32*    hbuf   = (u32*)(ws + 34406400);           // 64 KB
    u32*    flags  = (u32*)(ws + 34471936);           // 2 KB

    init_kernel<<<2, 256, 0, stream>>>(flags);
    pack_kernel<<<208, 256, 0, stream>>>(w_ih, w_hh, clf_w, Apack, Aipack, Wcq);

    void* args[] = {(void*)&inp, (void*)&bias, (void*)&Apack, (void*)&Aipack,
                    (void*)&Hs, (void*)&hbuf, (void*)&flags};
    hipLaunchCooperativeKernel((const void*)lstm_rec,
                               dim3(NGRP * NMEM), dim3(256), args, 0, stream);

    clf_kernel<<<BSZ * (TLEN / CTT), 256, 0, stream>>>(Wcq, Hs, clf_b, out);
}